// Round 7
// baseline (257.901 us; speedup 1.0000x reference)
//
#include <hip/hip_runtime.h>
#include <math.h>

#define H 64
#define NN 512
#define NB 2
#define NL 3
#define NBLK (NN * NB)

typedef _Float16 half8  __attribute__((ext_vector_type(8)));
typedef __fp16   fp16x2 __attribute__((ext_vector_type(2)));
typedef float    float4v __attribute__((ext_vector_type(4)));

union FragU { half8 h; unsigned int u[4]; uint4 q4; };
union F8    { float4 v4[2]; float f[8]; };

__device__ __forceinline__ float silu_f(float x) {
    float e = __expf(-x);
    return x * __builtin_amdgcn_rcpf(1.0f + e);
}

__device__ __forceinline__ unsigned int pk2(float a, float b) {
    fp16x2 h = __builtin_amdgcn_cvt_pkrtz(a, b);
    return __builtin_bit_cast(unsigned int, h);
}

// ---------------------------------------------------------------------------
// K0: merged setup: blocks 0..5 pack ew2/fw1 into MFMA A-frag layout; all
// blocks compute h0 + layer-0 P/Q (k-split across 4 waves) + zero faccum.
// R14: Q carries the sp_j * ew1[row130] term folded in (j-only quantity).
// ---------------------------------------------------------------------------
__global__ __launch_bounds__(256) void k_setup(
    const float* __restrict__ state, const float* __restrict__ hiw,
    const float* __restrict__ hib, const float* __restrict__ ew1,
    const float* __restrict__ eb1, const float* __restrict__ ew2,
    const float* __restrict__ fw1, float* __restrict__ h,
    float* __restrict__ P, float* __restrict__ Q, float* __restrict__ faccum,
    uint4* __restrict__ wpack)
{
    const int bn  = blockIdx.x;
    const int tid = threadIdx.x;
    const int wv  = tid >> 6;
    const int lane = tid & 63;

    __shared__ float sh[64];
    __shared__ float sRed[4][64];
    __shared__ float sRedQ[4][64];

    if (tid < 64) {
        const float* st = state + bn * 4;
        float vx = st[2], vy = st[3];
        float s2 = vx * vx + vy * vy;
        if (tid < 2) faccum[bn * 2 + tid] = 0.0f;
        float hv = silu_f(sqrtf(s2) * hiw[tid] + hib[tid]);
        h[(size_t)bn * H + tid] = hv;
        sh[tid] = hv;
    }
    if (bn < 6) {
        const int pl = bn >> 1, mat = bn & 1;
        const float* src = (mat ? fw1 : ew2) + (size_t)pl * 4096;
        uint4* dst = wpack + ((size_t)pl * 2 + mat) * 512;
        for (int g = tid; g < 512; g += 256) {
            int f = g >> 6, ln = g & 63;
            int mt = f >> 1, kt = f & 1, qq = ln >> 4, mm = ln & 15;
            int cm  = mt * 16 + mm;
            int cin = kt * 32 + qq * 8;
            uint4 u;
            u.x = pk2(src[(cin + 0) * 64 + cm], src[(cin + 1) * 64 + cm]);
            u.y = pk2(src[(cin + 2) * 64 + cm], src[(cin + 3) * 64 + cm]);
            u.z = pk2(src[(cin + 4) * 64 + cm], src[(cin + 5) * 64 + cm]);
            u.w = pk2(src[(cin + 6) * 64 + cm], src[(cin + 7) * 64 + cm]);
            dst[g] = u;
        }
    }
    __syncthreads();

    {
        float pp = 0.0f, qp = 0.0f;
        const float* wp = ew1 + (size_t)(wv * 16) * 64 + lane;
        const float* wq = ew1 + (size_t)(64 + wv * 16) * 64 + lane;
#pragma unroll 8
        for (int k = 0; k < 16; k++) {
            float hk = sh[wv * 16 + k];
            pp += hk * wp[(size_t)k * 64];
            qp += hk * wq[(size_t)k * 64];
        }
        sRed[wv][lane]  = pp;
        sRedQ[wv][lane] = qp;
    }
    __syncthreads();
    if (wv == 0) {
        const float* st = state + bn * 4;
        float vx = st[2], vy = st[3];
        float s2 = vx * vx + vy * vy;
        P[(size_t)bn * 64 + lane] = eb1[lane] + sRed[0][lane] + sRed[1][lane]
                                  + sRed[2][lane] + sRed[3][lane];
        Q[(size_t)bn * 64 + lane] = sRedQ[0][lane] + sRedQ[1][lane]
                                  + sRedQ[2][lane] + sRedQ[3][lane]
                                  + s2 * ew1[130 * 64 + lane];
    }
}

// ---------------------------------------------------------------------------
// Edge body: consumes a PRELOADED Q row (R20). Everything else as R19
// minus setprio (suspected small negative, T5 GEMM-null regime).
// ---------------------------------------------------------------------------
__device__ __forceinline__ void edge_body(
    int ck, int i, int b, int wv, int q, int m,
    const float4 sti,
    const float* __restrict__ state, const F8* __restrict__ qvP,
    const float* __restrict__ sW, const float* __restrict__ sBias,
    const float* __restrict__ sPB, unsigned short* __restrict__ MT,
    const FragU* __restrict__ wreg, const FragU* __restrict__ freg,
    const float4* __restrict__ fw2r,
    float* __restrict__ maccp, float fb2q, float& fax, float& fay)
{
    unsigned swoff = 0;
    asm volatile("" : "+v"(swoff));
    __builtin_assume((swoff & 3u) == 0);

    const int jg = wv * 128 + ck * 16 + m;
    const float msk = (jg != i) ? 1.0f : 0.0f;

    // ---- geometry + X1 B-fragments (Q from prefetched regs) ----
    float jnx, jny;
    FragU xb[2];
    {
        const float4 stj = *(const float4*)&state[(size_t)(b * NN + jg) * 4];
        float dx = stj.x - sti.x, dy = stj.y - sti.y;
        float ds = dx * dx + dy * dy;
        float rs = __builtin_amdgcn_rsqf(ds + 1e-8f);
        jnx = dx * rs;
        jny = dy * rs;
        float jap = (stj.z - sti.z) * jnx + (stj.w - sti.w) * jny;

#pragma unroll
        for (int kt = 0; kt < 2; kt++) {
            const int c0 = kt * 32 + q * 8;
            F8 w0, w3, pb;
            w0.v4[0] = *(const float4*)&sW[swoff + c0];
            w0.v4[1] = *(const float4*)&sW[swoff + c0 + 4];
            w3.v4[0] = *(const float4*)&sW[swoff + 64 + c0];
            w3.v4[1] = *(const float4*)&sW[swoff + 64 + c0 + 4];
            pb.v4[0] = *(const float4*)&sPB[swoff + c0];
            pb.v4[1] = *(const float4*)&sPB[swoff + c0 + 4];

            float xv[8];
#pragma unroll
            for (int d = 0; d < 8; d++) {
                float pre = pb.f[d] + qvP[kt].f[d] + ds * w0.f[d]
                          + jap * w3.f[d];
                xv[d] = silu_f(pre);
            }
#pragma unroll
            for (int d = 0; d < 4; d++)
                xb[kt].u[d] = pk2(xv[2 * d], xv[2 * d + 1]);
        }
    }

    // ---- GEMM1 in two sequential mt-halves ----
#pragma unroll
    for (int hf = 0; hf < 2; hf++) {
        float4v acc[2];
#pragma unroll
        for (int mt2 = 0; mt2 < 2; mt2++) {
            const float4 b2v = *(const float4*)&sBias[swoff + (hf * 2 + mt2) * 16 + q * 4];
            acc[mt2][0] = b2v.x; acc[mt2][1] = b2v.y;
            acc[mt2][2] = b2v.z; acc[mt2][3] = b2v.w;
        }
#pragma unroll
        for (int kt = 0; kt < 2; kt++) {
#pragma unroll
            for (int mt2 = 0; mt2 < 2; mt2++) {
                acc[mt2] = __builtin_amdgcn_mfma_f32_16x16x32_f16(
                    wreg[(hf * 2 + mt2) * 2 + kt].h, xb[kt].h, acc[mt2], 0, 0, 0);
            }
        }
        // epilogue 1: silu, magg partials (mask-FMA), transpose to LDS
#pragma unroll
        for (int mt2 = 0; mt2 < 2; mt2++) {
            const int mt = hf * 2 + mt2;
            float4v a = acc[mt2];
            float m0 = silu_f(a[0]);
            float m1 = silu_f(a[1]);
            float m2 = silu_f(a[2]);
            float m3 = silu_f(a[3]);
            maccp[mt * 4 + 0] = fmaf(m0, msk, maccp[mt * 4 + 0]);
            maccp[mt * 4 + 1] = fmaf(m1, msk, maccp[mt * 4 + 1]);
            maccp[mt * 4 + 2] = fmaf(m2, msk, maccp[mt * 4 + 2]);
            maccp[mt * 4 + 3] = fmaf(m3, msk, maccp[mt * 4 + 3]);
            uint2 dw = make_uint2(pk2(m0, m1), pk2(m2, m3));
            *(uint2*)&MT[m * 72 + mt * 16 + q * 4] = dw;   // wave-private
        }
    }

    // ---- GEMM2 in two sequential mt-halves ----
    float fdp = 0.0f;
    FragU xb2[2];
#pragma unroll
    for (int kt = 0; kt < 2; kt++)
        xb2[kt].q4 = *(uint4*)&MT[m * 72 + kt * 32 + q * 8];
#pragma unroll
    for (int hf = 0; hf < 2; hf++) {
        float4v acc2[2];
#pragma unroll
        for (int mt2 = 0; mt2 < 2; mt2++) {
            const float4 fb1v = *(const float4*)&sBias[swoff + 64 + (hf * 2 + mt2) * 16 + q * 4];
            acc2[mt2][0] = fb1v.x; acc2[mt2][1] = fb1v.y;
            acc2[mt2][2] = fb1v.z; acc2[mt2][3] = fb1v.w;
        }
#pragma unroll
        for (int kt = 0; kt < 2; kt++) {
#pragma unroll
            for (int mt2 = 0; mt2 < 2; mt2++) {
                acc2[mt2] = __builtin_amdgcn_mfma_f32_16x16x32_f16(
                    freg[(hf * 2 + mt2) * 2 + kt].h, xb2[kt].h, acc2[mt2], 0, 0, 0);
            }
        }
        // epilogue 2: silu + dot with fw2 (registers)
#pragma unroll
        for (int mt2 = 0; mt2 < 2; mt2++) {
            const float4 fw2v = fw2r[hf * 2 + mt2];
            float4v a = acc2[mt2];
            fdp += silu_f(a[0]) * fw2v.x
                 + silu_f(a[1]) * fw2v.y
                 + silu_f(a[2]) * fw2v.z
                 + silu_f(a[3]) * fw2v.w;
        }
    }

    // q-partial dot; fb2 enters as /4; j==i auto-masked (normal == 0)
    float fd = fdp + fb2q;
    fax += fd * jnx;
    fay += fd * jny;
}

// ---------------------------------------------------------------------------
// K2: fused edge + node + next-layer-PQ kernel. Block = 256 thr = 4 waves.
// R13: weight MFMA-fragments (ew2 AND fw1) live in VGPRs (64 regs).
// R14: sp_j folded into Q; force dot via q-partials (no per-ck shuffles).
// R19: mask-FMA maccp; fw2 hoisted to regs.
// R20: Q row PREFETCHED one ck ahead via explicit A/B register pair in a
//      2-ck ping-pong body (no dynamic indexing, no reg copies). R11's
//      prefetch failure was the 128-VGPR cliff (144 regs); we now have
//      headroom (104 -> ~120). setprio dropped (R19 slight negative,
//      GEMM-null regime per T5).
// FAILED/NULL log: R15 spill; R16 skew null; R17 i-pair null; R18 j-split
// regression; R19 trims null. Pipe-sum: all pipes <33% of wall -> stall-
// dominated; scattered L2 Q-reads are the last unattacked latency source.
// NOTE (R10): no single-kernel grid barriers — cross-XCD coherence = 800 us.
// NOTE (R15): never give __launch_bounds__ a min-waves clamp here (spills).
// ---------------------------------------------------------------------------
__global__ __launch_bounds__(256) void k_edge(
    const float* __restrict__ state,
    const float* __restrict__ P, const float* __restrict__ Q,
    float* __restrict__ Pout, float* __restrict__ Qout,
    const float* __restrict__ ew1_l,
    const uint4* __restrict__ wpackL,     // [0..511]=ew2 frags, [512..1023]=fw1
    const float* __restrict__ eb2_l,
    const float* __restrict__ fb1_l,
    const float* __restrict__ fw2_l, const float* __restrict__ fb2_l,
    float* __restrict__ h, float* __restrict__ faccum,
    const float* __restrict__ nw1_l, const float* __restrict__ nb1_l,
    const float* __restrict__ nw2_l, const float* __restrict__ nb2_l,
    const float* __restrict__ ew1_n, const float* __restrict__ eb1_n,
    const float* __restrict__ ww1, const float* __restrict__ wb1,
    const float* __restrict__ ww2, const float* __restrict__ wb2,
    const float* __restrict__ ww3, const float* __restrict__ wb3,
    float* __restrict__ out, int last)
{
    const int i    = blockIdx.x;
    const int b    = blockIdx.y;
    const int tid  = threadIdx.x;
    const int wv   = tid >> 6;
    const int lane = tid & 63;
    const int q    = lane >> 4;   // quad 0..3
    const int m    = lane & 15;   // 0..15
    const int bn_i = b * NN + i;

    __shared__ float sW[128];                   // ew1 rows 128 (ds), 131 (ap)
    __shared__ float sBias[192];                // eb2 | fb1 | fw2
    __shared__ float sPB[64];                   // P_i + spi*w129 (block-level)
    __shared__ __align__(16) unsigned short sMT[4][16 * 72]; // per-wave M^T
    __shared__ float sRed[4][64];               // partials per wave
    __shared__ float sRedQ[4][64];              // Q partials (pq tail)
    __shared__ float sF[4][2];                  // force partials per wave

    if (tid < 128) sW[tid] = ew1_l[(128 + (tid >> 6) * 3) * 64 + (tid & 63)];
    if (tid < 192) sBias[tid] = (tid < 64) ? eb2_l[tid]
                              : (tid < 128) ? fb1_l[tid - 64]
                              : fw2_l[tid - 128];

    // ---- weight MFMA fragments -> VGPRs, once (L2-resident, coalesced) ----
    FragU wreg[8], freg[8];
#pragma unroll
    for (int f = 0; f < 8; f++) {
        wreg[f].q4 = wpackL[f * 64 + lane];
        freg[f].q4 = wpackL[512 + f * 64 + lane];
    }

    const float4 sti = *(const float4*)&state[(size_t)bn_i * 4];
    const float  spi = sti.z * sti.z + sti.w * sti.w;
    if (tid < 64) sPB[tid] = P[(size_t)bn_i * 64 + tid] + spi * ew1_l[129 * 64 + tid];
    __syncthreads();

    const float fb2q = fb2_l[0] * 0.25f;

    // fw2 per-lane values hoisted to registers: loop-invariant.
    float4 fw2r[4];
#pragma unroll
    for (int mt = 0; mt < 4; mt++)
        fw2r[mt] = *(const float4*)&sBias[128 + mt * 16 + q * 4];

    float maccp[16];
#pragma unroll
    for (int t = 0; t < 16; t++) maccp[t] = 0.0f;
    float fax = 0.0f, fay = 0.0f;

    // ---- Q-prefetch helper: 16 floats (one row slice per lane) ----
    const float* Qbase = Q + (size_t)(b * NN) * 64 + q * 8;
    auto loadQ = [&](int ck, F8* qv) {
        const int jg = wv * 128 + ck * 16 + m;
        const float* Qr = Qbase + (size_t)jg * 64;
        qv[0].v4[0] = *(const float4*)Qr;
        qv[0].v4[1] = *(const float4*)(Qr + 4);
        qv[1].v4[0] = *(const float4*)(Qr + 32);
        qv[1].v4[1] = *(const float4*)(Qr + 36);
    };

    F8 qvA[2], qvB[2];
    loadQ(0, qvA);

#pragma unroll 1
    for (int ck2 = 0; ck2 < 4; ck2++) {
        const int cka = ck2 * 2;
        loadQ(cka + 1, qvB);                       // prefetch odd ck
        edge_body(cka, i, b, wv, q, m, sti, state, qvA,
                  sW, sBias, sPB, sMT[wv], wreg, freg, fw2r,
                  maccp, fb2q, fax, fay);
        loadQ((cka + 2) & 7, qvA);                 // prefetch next even ck
        edge_body(cka + 1, i, b, wv, q, m, sti, state, qvB,
                  sW, sBias, sPB, sMT[wv], wreg, freg, fw2r,
                  maccp, fb2q, fax, fay);
    }

    // ---- per-wave reductions into LDS ----
#pragma unroll
    for (int t = 0; t < 16; t++) {
        float v = maccp[t];
        v += __shfl_xor(v, 1, 64);
        v += __shfl_xor(v, 2, 64);
        v += __shfl_xor(v, 4, 64);
        v += __shfl_xor(v, 8, 64);
        maccp[t] = v;
    }
    if (m == 0) {
#pragma unroll
        for (int mt = 0; mt < 4; mt++)
#pragma unroll
          for (int r = 0; r < 4; r++)
            sRed[wv][mt * 16 + q * 4 + r] = maccp[mt * 4 + r];
    }
#pragma unroll
    for (int off = 1; off < 64; off <<= 1) {
        fax += __shfl_xor(fax, off, 64);
        fay += __shfl_xor(fay, off, 64);
    }
    if (lane == 0) {
        sF[wv][0] = fax;   // q-partials already included in the 64-lane sum
        sF[wv][1] = fay;
    }
    __syncthreads();                                   // B1

    // ---- node MLP tail, k-split across all 4 waves ----
    float* scr = (float*)sMT;
    const int c = lane;
    if (wv == 0) {
        float magg = sRed[0][c] + sRed[1][c] + sRed[2][c] + sRed[3][c];
        scr[c]      = h[(size_t)bn_i * 64 + c];
        scr[64 + c] = magg;
    }
    __syncthreads();                                   // B2

    {
        float part = 0.0f;
        const float* w = nw1_l + (size_t)(wv * 32) * 64 + c;
#pragma unroll 8
        for (int k = 0; k < 32; k++) part += scr[wv * 32 + k] * w[(size_t)k * 64];
        sRed[wv][c] = part;
    }
    __syncthreads();                                   // B3
    if (wv == 0) {
        float t1 = nb1_l[c] + sRed[0][c] + sRed[1][c] + sRed[2][c] + sRed[3][c];
        scr[128 + c] = silu_f(t1);
    }
    __syncthreads();                                   // B4

    {
        float part = 0.0f;
        const float* w = nw2_l + (size_t)(wv * 16) * 64 + c;
#pragma unroll 8
        for (int k = 0; k < 16; k++) part += scr[128 + wv * 16 + k] * w[(size_t)k * 64];
        sRed[wv][c] = part;
    }
    __syncthreads();                                   // B5

    if (wv == 0) {
        float hn  = nb2_l[c] + sRed[0][c] + sRed[1][c] + sRed[2][c] + sRed[3][c];
        scr[192 + c] = hn;
        if (!last) {
            h[(size_t)bn_i * 64 + c] = hn;
            float fxl = sF[0][0] + sF[1][0] + sF[2][0] + sF[3][0];
            float fyl = sF[0][1] + sF[1][1] + sF[2][1] + sF[3][1];
            if (c == 0) {
                faccum[bn_i * 2 + 0] += fxl;
                faccum[bn_i * 2 + 1] += fyl;
            }
        }
    }
    __syncthreads();                                   // B6

    if (!last) {
        // ---- next-layer P/Q, k-split across 4 waves -> PING-PONG buffer ----
        float pp = 0.0f, qp = 0.0f;
        const float* wp = ew1_n + (size_t)(wv * 16) * 64 + c;
        const float* wq = ew1_n + (size_t)(64 + wv * 16) * 64 + c;
#pragma unroll 8
        for (int k = 0; k < 16; k++) {
            float hk = scr[192 + wv * 16 + k];
            pp += hk * wp[(size_t)k * 64];
            qp += hk * wq[(size_t)k * 64];
        }
        sRed[wv][c]  = pp;
        sRedQ[wv][c] = qp;
        __syncthreads();                               // B7
        if (wv == 0) {
            Pout[(size_t)bn_i * 64 + c] = eb1_n[c] + sRed[0][c] + sRed[1][c]
                                        + sRed[2][c] + sRed[3][c];
            Qout[(size_t)bn_i * 64 + c] = sRedQ[0][c] + sRedQ[1][c]
                                        + sRedQ[2][c] + sRedQ[3][c]
                                        + spi * ew1_n[130 * 64 + c];
        }
        return;
    }

    if (wv != 0) return;

    // ---- wall MLP + final output (last layer only, wave 0) ----
    if (c < 4) {
        float px = sti.x, py = sti.y;
        float wd = (c == 0) ? px : (c == 1) ? 1.0f - px : (c == 2) ? py : 1.0f - py;
        scr[256 + c] = wd;
    }
    float t2 = wb1[c];
#pragma unroll 4
    for (int k = 0; k < 64; k++) t2 += scr[192 + k] * ww1[k * 64 + c];
#pragma unroll
    for (int k = 0; k < 4; k++)  t2 += scr[256 + k] * ww1[(64 + k) * 64 + c];
    t2 = silu_f(t2);
    scr[320 + c] = t2;
    float u = wb2[c];
#pragma unroll 8
    for (int k = 0; k < 64; k++) u += scr[320 + k] * ww2[k * 64 + c];
    u = silu_f(u);
    scr[384 + c] = u;
    if (c < 4) {
        float mg = wb3[c];
        for (int k = 0; k < 64; k++) mg += scr[384 + k] * ww3[k * 4 + c];
        scr[448 + c] = mg;
    }
    if (c == 0) {
        float fxl = sF[0][0] + sF[1][0] + sF[2][0] + sF[3][0];
        float fyl = sF[0][1] + sF[1][1] + sF[2][1] + sF[3][1];
        float fx = faccum[bn_i * 2 + 0] + fxl + (scr[448 + 0] - scr[448 + 1]);
        float fy = faccum[bn_i * 2 + 1] + fyl + (scr[448 + 2] - scr[448 + 3]);
        out[bn_i * 2 + 0] = fx;
        out[bn_i * 2 + 1] = fy;
    }
}

// ---------------------------------------------------------------------------
extern "C" void kernel_launch(void* const* d_in, const int* in_sizes, int n_in,
                              void* d_out, int out_size, void* d_ws, size_t ws_size,
                              hipStream_t stream)
{
    const float* state = (const float*)d_in[0];
    const float* hiw   = (const float*)d_in[1];
    const float* hib   = (const float*)d_in[2];
    const float* ew1   = (const float*)d_in[3];   // (3,132,64)
    const float* eb1   = (const float*)d_in[4];   // (3,64)
    const float* ew2   = (const float*)d_in[5];   // (3,64,64)
    const float* eb2   = (const float*)d_in[6];
    const float* fw1   = (const float*)d_in[7];   // (3,64,64)
    const float* fb1   = (const float*)d_in[8];
    const float* fw2   = (const float*)d_in[9];   // (3,64,1)
    const float* fb2   = (const float*)d_in[10];  // (3,1)
    const float* nw1   = (const float*)d_in[11];  // (3,128,64)
    const float* nb1   = (const float*)d_in[12];
    const float* nw2   = (const float*)d_in[13];  // (3,64,64)
    const float* nb2   = (const float*)d_in[14];
    const float* ww1   = (const float*)d_in[15];  // (68,64)
    const float* wb1   = (const float*)d_in[16];
    const float* ww2   = (const float*)d_in[17];  // (64,64)
    const float* wb2   = (const float*)d_in[18];
    const float* ww3   = (const float*)d_in[19];  // (64,4)
    const float* wb3   = (const float*)d_in[20];
    float* out = (float*)d_out;

    float* ws     = (float*)d_ws;
    float* h      = ws;                               // NB*NN*H
    float* P0     = h      + (size_t)NB * NN * H;
    float* Q0     = P0     + (size_t)NB * NN * H;
    float* P1     = Q0     + (size_t)NB * NN * H;     // ping-pong pair
    float* Q1     = P1     + (size_t)NB * NN * H;
    float* faccum = Q1     + (size_t)NB * NN * H;     // NB*NN*2
    float* wpackf = faccum + (size_t)NB * NN * 2;
    uint4* wpack  = (uint4*)(((uintptr_t)wpackf + 15) & ~(uintptr_t)15);

    float* Pb[2] = { P0, P1 };
    float* Qb[2] = { Q0, Q1 };

    k_setup<<<NBLK, 256, 0, stream>>>(state, hiw, hib, ew1, eb1,
                                      ew2, fw1, h, P0, Q0, faccum, wpack);

    for (int l = 0; l < NL; l++) {
        const int last = (l == NL - 1) ? 1 : 0;
        const int nl = last ? 0 : (l + 1);
        const int cur = l & 1, nxt = (l + 1) & 1;
        k_edge<<<dim3(NN, NB), 256, 0, stream>>>(
            state, Pb[cur], Qb[cur], Pb[nxt], Qb[nxt],
            ew1 + (size_t)l * 132 * 64,
            wpack + (size_t)l * 1024,
            eb2 + (size_t)l * 64,
            fb1 + (size_t)l * 64,
            fw2 + (size_t)l * 64, fb2 + (size_t)l,
            h, faccum,
            nw1 + (size_t)l * 128 * 64, nb1 + (size_t)l * 64,
            nw2 + (size_t)l * 64 * 64,  nb2 + (size_t)l * 64,
            ew1 + (size_t)nl * 132 * 64, eb1 + (size_t)nl * 64,
            ww1, wb1, ww2, wb2, ww3, wb3,
            out, last);
    }
}

// Round 8
// 230.972 us; speedup vs baseline: 1.1166x; 1.1166x over previous
//
#include <hip/hip_runtime.h>
#include <math.h>

#define H 64
#define NN 512
#define NB 2
#define NL 3
#define NBLK (NN * NB)

typedef _Float16 half8  __attribute__((ext_vector_type(8)));
typedef __fp16   fp16x2 __attribute__((ext_vector_type(2)));
typedef float    float4v __attribute__((ext_vector_type(4)));

union FragU { half8 h; unsigned int u[4]; uint4 q4; };
union F8    { float4 v4[2]; float f[8]; };

__device__ __forceinline__ float silu_f(float x) {
    float e = __expf(-x);
    return x * __builtin_amdgcn_rcpf(1.0f + e);
}

__device__ __forceinline__ unsigned int pk2(float a, float b) {
    fp16x2 h = __builtin_amdgcn_cvt_pkrtz(a, b);
    return __builtin_bit_cast(unsigned int, h);
}

// ---------------------------------------------------------------------------
// K0: merged setup: blocks 0..5 pack ew2/fw1 into MFMA A-frag layout; all
// blocks compute h0 + layer-0 P/Q (k-split across 4 waves) + zero faccum.
// R14: Q carries the sp_j * ew1[row130] term folded in (j-only quantity).
// ---------------------------------------------------------------------------
__global__ __launch_bounds__(256) void k_setup(
    const float* __restrict__ state, const float* __restrict__ hiw,
    const float* __restrict__ hib, const float* __restrict__ ew1,
    const float* __restrict__ eb1, const float* __restrict__ ew2,
    const float* __restrict__ fw1, float* __restrict__ h,
    float* __restrict__ P, float* __restrict__ Q, float* __restrict__ faccum,
    uint4* __restrict__ wpack)
{
    const int bn  = blockIdx.x;
    const int tid = threadIdx.x;
    const int wv  = tid >> 6;
    const int lane = tid & 63;

    __shared__ float sh[64];
    __shared__ float sRed[4][64];
    __shared__ float sRedQ[4][64];

    if (tid < 64) {
        const float* st = state + bn * 4;
        float vx = st[2], vy = st[3];
        float s2 = vx * vx + vy * vy;
        if (tid < 2) faccum[bn * 2 + tid] = 0.0f;
        float hv = silu_f(sqrtf(s2) * hiw[tid] + hib[tid]);
        h[(size_t)bn * H + tid] = hv;
        sh[tid] = hv;
    }
    if (bn < 6) {
        const int pl = bn >> 1, mat = bn & 1;
        const float* src = (mat ? fw1 : ew2) + (size_t)pl * 4096;
        uint4* dst = wpack + ((size_t)pl * 2 + mat) * 512;
        for (int g = tid; g < 512; g += 256) {
            int f = g >> 6, ln = g & 63;
            int mt = f >> 1, kt = f & 1, qq = ln >> 4, mm = ln & 15;
            int cm  = mt * 16 + mm;
            int cin = kt * 32 + qq * 8;
            uint4 u;
            u.x = pk2(src[(cin + 0) * 64 + cm], src[(cin + 1) * 64 + cm]);
            u.y = pk2(src[(cin + 2) * 64 + cm], src[(cin + 3) * 64 + cm]);
            u.z = pk2(src[(cin + 4) * 64 + cm], src[(cin + 5) * 64 + cm]);
            u.w = pk2(src[(cin + 6) * 64 + cm], src[(cin + 7) * 64 + cm]);
            dst[g] = u;
        }
    }
    __syncthreads();

    {
        float pp = 0.0f, qp = 0.0f;
        const float* wp = ew1 + (size_t)(wv * 16) * 64 + lane;
        const float* wq = ew1 + (size_t)(64 + wv * 16) * 64 + lane;
#pragma unroll 8
        for (int k = 0; k < 16; k++) {
            float hk = sh[wv * 16 + k];
            pp += hk * wp[(size_t)k * 64];
            qp += hk * wq[(size_t)k * 64];
        }
        sRed[wv][lane]  = pp;
        sRedQ[wv][lane] = qp;
    }
    __syncthreads();
    if (wv == 0) {
        const float* st = state + bn * 4;
        float vx = st[2], vy = st[3];
        float s2 = vx * vx + vy * vy;
        P[(size_t)bn * 64 + lane] = eb1[lane] + sRed[0][lane] + sRed[1][lane]
                                  + sRed[2][lane] + sRed[3][lane];
        Q[(size_t)bn * 64 + lane] = sRedQ[0][lane] + sRedQ[1][lane]
                                  + sRedQ[2][lane] + sRedQ[3][lane]
                                  + s2 * ew1[130 * 64 + lane];
    }
}

// ---------------------------------------------------------------------------
// K2 (R21): REGISTER-RESIDENT inner loop. __launch_bounds__(256, 2) lifts
// the VGPR cap to 256 (2 waves/SIMD); the anti-LICM guard is DELETED so
// LICM hoists all loop-invariant LDS reads (w0/w3/pb/b2v/fb1/fw2 = 96 f32)
// into registers alongside wreg/freg. In-loop DS drops 26 -> 6 ops/ck (the
// MT transpose only): DS pipe ~13.8 -> ~3.5 us of the convoy sum.
// Rationale: R17/R18 proved extra waves buy nothing (convoy-bound, pipes
// alternately saturated); so occupancy is sold for registers. R15's spill
// disaster was a RESTRICTIVE cap (128 < need); 256 > need (~230) is safe.
// R13: wreg/freg in VGPRs. R14: sp_j folded into Q; force via q-partials.
// FAILED/NULL log: R15 spill; R16 skew null; R17 i-pair null; R18 j-split
// regression; R19 trims null; R20 Q-prefetch -18%.
// NOTE (R10): no single-kernel grid barriers — cross-XCD coherence = 800 us.
// ---------------------------------------------------------------------------
__global__ __launch_bounds__(256, 2) void k_edge(
    const float* __restrict__ state,
    const float* __restrict__ P, const float* __restrict__ Q,
    float* __restrict__ Pout, float* __restrict__ Qout,
    const float* __restrict__ ew1_l,
    const uint4* __restrict__ wpackL,     // [0..511]=ew2 frags, [512..1023]=fw1
    const float* __restrict__ eb2_l,
    const float* __restrict__ fb1_l,
    const float* __restrict__ fw2_l, const float* __restrict__ fb2_l,
    float* __restrict__ h, float* __restrict__ faccum,
    const float* __restrict__ nw1_l, const float* __restrict__ nb1_l,
    const float* __restrict__ nw2_l, const float* __restrict__ nb2_l,
    const float* __restrict__ ew1_n, const float* __restrict__ eb1_n,
    const float* __restrict__ ww1, const float* __restrict__ wb1,
    const float* __restrict__ ww2, const float* __restrict__ wb2,
    const float* __restrict__ ww3, const float* __restrict__ wb3,
    float* __restrict__ out, int last)
{
    const int i    = blockIdx.x;
    const int b    = blockIdx.y;
    const int tid  = threadIdx.x;
    const int wv   = tid >> 6;
    const int lane = tid & 63;
    const int q    = lane >> 4;   // quad 0..3
    const int m    = lane & 15;   // 0..15
    const int bn_i = b * NN + i;

    __shared__ float sW[128];                   // ew1 rows 128 (ds), 131 (ap)
    __shared__ float sBias[192];                // eb2 | fb1 | fw2
    __shared__ float sPB[64];                   // P_i + spi*w129 (block-level)
    __shared__ __align__(16) unsigned short sMT[4][16 * 72]; // per-wave M^T
    __shared__ float sRed[4][64];               // partials per wave
    __shared__ float sRedQ[4][64];              // Q partials (pq tail)
    __shared__ float sF[4][2];                  // force partials per wave

    if (tid < 128) sW[tid] = ew1_l[(128 + (tid >> 6) * 3) * 64 + (tid & 63)];
    if (tid < 192) sBias[tid] = (tid < 64) ? eb2_l[tid]
                              : (tid < 128) ? fb1_l[tid - 64]
                              : fw2_l[tid - 128];

    // ---- weight MFMA fragments -> VGPRs, once (L2-resident, coalesced) ----
    FragU wreg[8], freg[8];
#pragma unroll
    for (int f = 0; f < 8; f++) {
        wreg[f].q4 = wpackL[f * 64 + lane];
        freg[f].q4 = wpackL[512 + f * 64 + lane];
    }

    const float4 sti = *(const float4*)&state[(size_t)bn_i * 4];
    const float  spi = sti.z * sti.z + sti.w * sti.w;
    if (tid < 64) sPB[tid] = P[(size_t)bn_i * 64 + tid] + spi * ew1_l[129 * 64 + tid];
    __syncthreads();

    const float fb2q = fb2_l[0] * 0.25f;

    // ---- hoist ALL loop-invariant LDS data to registers (LICM-friendly,
    //      explicit so the liveness is obvious): 96 f32 ----
    F8 w0r[2], w3r[2], pbr[2];
    float4 b2r[4], fb1r[4], fw2r[4];
#pragma unroll
    for (int kt = 0; kt < 2; kt++) {
        const int c0 = kt * 32 + q * 8;
        w0r[kt].v4[0] = *(const float4*)&sW[c0];
        w0r[kt].v4[1] = *(const float4*)&sW[c0 + 4];
        w3r[kt].v4[0] = *(const float4*)&sW[64 + c0];
        w3r[kt].v4[1] = *(const float4*)&sW[64 + c0 + 4];
        pbr[kt].v4[0] = *(const float4*)&sPB[c0];
        pbr[kt].v4[1] = *(const float4*)&sPB[c0 + 4];
    }
#pragma unroll
    for (int mt = 0; mt < 4; mt++) {
        b2r[mt]  = *(const float4*)&sBias[mt * 16 + q * 4];
        fb1r[mt] = *(const float4*)&sBias[64 + mt * 16 + q * 4];
        fw2r[mt] = *(const float4*)&sBias[128 + mt * 16 + q * 4];
    }

    float maccp[16];
#pragma unroll
    for (int t = 0; t < 16; t++) maccp[t] = 0.0f;
    float fax = 0.0f, fay = 0.0f;

    unsigned short* MT = sMT[wv];

#pragma unroll 1
    for (int ck = 0; ck < 8; ck++) {
        const int jg = wv * 128 + ck * 16 + m;   // this lane's j
        const float msk = (jg != i) ? 1.0f : 0.0f;

        // ---- geometry + X1 B-fragments (all operands in regs except Q) ----
        float jnx, jny;
        FragU xb[2];
        {
            const float4 stj = *(const float4*)&state[(size_t)(b * NN + jg) * 4];
            float dx = stj.x - sti.x, dy = stj.y - sti.y;
            float ds = dx * dx + dy * dy;
            float rs = __builtin_amdgcn_rsqf(ds + 1e-8f);
            jnx = dx * rs;
            jny = dy * rs;
            float jap = (stj.z - sti.z) * jnx + (stj.w - sti.w) * jny;

#pragma unroll
            for (int kt = 0; kt < 2; kt++) {
                const int c0 = kt * 32 + q * 8;
                const float* Qr = &Q[(size_t)(b * NN + jg) * 64 + c0];
                F8 qv;
                qv.v4[0] = *(const float4*)Qr;
                qv.v4[1] = *(const float4*)(Qr + 4);
                float xv[8];
#pragma unroll
                for (int d = 0; d < 8; d++) {
                    float pre = pbr[kt].f[d] + qv.f[d] + ds * w0r[kt].f[d]
                              + jap * w3r[kt].f[d];
                    xv[d] = silu_f(pre);
                }
#pragma unroll
                for (int d = 0; d < 4; d++)
                    xb[kt].u[d] = pk2(xv[2 * d], xv[2 * d + 1]);
            }
        }

        // ---- GEMM1 in two sequential mt-halves ----
#pragma unroll
        for (int hf = 0; hf < 2; hf++) {
            float4v acc[2];
#pragma unroll
            for (int mt2 = 0; mt2 < 2; mt2++) {
                const float4 b2v = b2r[hf * 2 + mt2];
                acc[mt2][0] = b2v.x; acc[mt2][1] = b2v.y;
                acc[mt2][2] = b2v.z; acc[mt2][3] = b2v.w;
            }
#pragma unroll
            for (int kt = 0; kt < 2; kt++) {
#pragma unroll
                for (int mt2 = 0; mt2 < 2; mt2++) {
                    acc[mt2] = __builtin_amdgcn_mfma_f32_16x16x32_f16(
                        wreg[(hf * 2 + mt2) * 2 + kt].h, xb[kt].h, acc[mt2], 0, 0, 0);
                }
            }
            // epilogue 1: silu, magg partials (mask-FMA), transpose to LDS
#pragma unroll
            for (int mt2 = 0; mt2 < 2; mt2++) {
                const int mt = hf * 2 + mt2;
                float4v a = acc[mt2];
                float m0 = silu_f(a[0]);
                float m1 = silu_f(a[1]);
                float m2 = silu_f(a[2]);
                float m3 = silu_f(a[3]);
                maccp[mt * 4 + 0] = fmaf(m0, msk, maccp[mt * 4 + 0]);
                maccp[mt * 4 + 1] = fmaf(m1, msk, maccp[mt * 4 + 1]);
                maccp[mt * 4 + 2] = fmaf(m2, msk, maccp[mt * 4 + 2]);
                maccp[mt * 4 + 3] = fmaf(m3, msk, maccp[mt * 4 + 3]);
                uint2 dw = make_uint2(pk2(m0, m1), pk2(m2, m3));
                *(uint2*)&MT[m * 72 + mt * 16 + q * 4] = dw;   // wave-private
            }
        }

        // ---- GEMM2 in two sequential mt-halves ----
        float fdp = 0.0f;
        FragU xb2[2];
#pragma unroll
        for (int kt = 0; kt < 2; kt++)
            xb2[kt].q4 = *(uint4*)&MT[m * 72 + kt * 32 + q * 8];
#pragma unroll
        for (int hf = 0; hf < 2; hf++) {
            float4v acc2[2];
#pragma unroll
            for (int mt2 = 0; mt2 < 2; mt2++) {
                const float4 fb1v = fb1r[hf * 2 + mt2];
                acc2[mt2][0] = fb1v.x; acc2[mt2][1] = fb1v.y;
                acc2[mt2][2] = fb1v.z; acc2[mt2][3] = fb1v.w;
            }
#pragma unroll
            for (int kt = 0; kt < 2; kt++) {
#pragma unroll
                for (int mt2 = 0; mt2 < 2; mt2++) {
                    acc2[mt2] = __builtin_amdgcn_mfma_f32_16x16x32_f16(
                        freg[(hf * 2 + mt2) * 2 + kt].h, xb2[kt].h, acc2[mt2], 0, 0, 0);
                }
            }
            // epilogue 2: silu + dot with fw2 (registers)
#pragma unroll
            for (int mt2 = 0; mt2 < 2; mt2++) {
                const float4 fw2v = fw2r[hf * 2 + mt2];
                float4v a = acc2[mt2];
                fdp += silu_f(a[0]) * fw2v.x
                     + silu_f(a[1]) * fw2v.y
                     + silu_f(a[2]) * fw2v.z
                     + silu_f(a[3]) * fw2v.w;
            }
        }

        {
            // q-partial dot; fb2 enters as /4; j==i auto-masked (normal == 0)
            float fd = fdp + fb2q;
            fax += fd * jnx;
            fay += fd * jny;
        }
    } // ck

    // ---- per-wave reductions into LDS ----
#pragma unroll
    for (int t = 0; t < 16; t++) {
        float v = maccp[t];
        v += __shfl_xor(v, 1, 64);
        v += __shfl_xor(v, 2, 64);
        v += __shfl_xor(v, 4, 64);
        v += __shfl_xor(v, 8, 64);
        maccp[t] = v;
    }
    if (m == 0) {
#pragma unroll
        for (int mt = 0; mt < 4; mt++)
#pragma unroll
          for (int r = 0; r < 4; r++)
            sRed[wv][mt * 16 + q * 4 + r] = maccp[mt * 4 + r];
    }
#pragma unroll
    for (int off = 1; off < 64; off <<= 1) {
        fax += __shfl_xor(fax, off, 64);
        fay += __shfl_xor(fay, off, 64);
    }
    if (lane == 0) {
        sF[wv][0] = fax;   // q-partials already included in the 64-lane sum
        sF[wv][1] = fay;
    }
    __syncthreads();                                   // B1

    // ---- node MLP tail, k-split across all 4 waves ----
    float* scr = (float*)sMT;
    const int c = lane;
    if (wv == 0) {
        float magg = sRed[0][c] + sRed[1][c] + sRed[2][c] + sRed[3][c];
        scr[c]      = h[(size_t)bn_i * 64 + c];
        scr[64 + c] = magg;
    }
    __syncthreads();                                   // B2

    {
        float part = 0.0f;
        const float* w = nw1_l + (size_t)(wv * 32) * 64 + c;
#pragma unroll 8
        for (int k = 0; k < 32; k++) part += scr[wv * 32 + k] * w[(size_t)k * 64];
        sRed[wv][c] = part;
    }
    __syncthreads();                                   // B3
    if (wv == 0) {
        float t1 = nb1_l[c] + sRed[0][c] + sRed[1][c] + sRed[2][c] + sRed[3][c];
        scr[128 + c] = silu_f(t1);
    }
    __syncthreads();                                   // B4

    {
        float part = 0.0f;
        const float* w = nw2_l + (size_t)(wv * 16) * 64 + c;
#pragma unroll 8
        for (int k = 0; k < 16; k++) part += scr[128 + wv * 16 + k] * w[(size_t)k * 64];
        sRed[wv][c] = part;
    }
    __syncthreads();                                   // B5

    if (wv == 0) {
        float hn  = nb2_l[c] + sRed[0][c] + sRed[1][c] + sRed[2][c] + sRed[3][c];
        scr[192 + c] = hn;
        if (!last) {
            h[(size_t)bn_i * 64 + c] = hn;
            float fxl = sF[0][0] + sF[1][0] + sF[2][0] + sF[3][0];
            float fyl = sF[0][1] + sF[1][1] + sF[2][1] + sF[3][1];
            if (c == 0) {
                faccum[bn_i * 2 + 0] += fxl;
                faccum[bn_i * 2 + 1] += fyl;
            }
        }
    }
    __syncthreads();                                   // B6

    if (!last) {
        // ---- next-layer P/Q, k-split across 4 waves -> PING-PONG buffer ----
        float pp = 0.0f, qp = 0.0f;
        const float* wp = ew1_n + (size_t)(wv * 16) * 64 + c;
        const float* wq = ew1_n + (size_t)(64 + wv * 16) * 64 + c;
#pragma unroll 8
        for (int k = 0; k < 16; k++) {
            float hk = scr[192 + wv * 16 + k];
            pp += hk * wp[(size_t)k * 64];
            qp += hk * wq[(size_t)k * 64];
        }
        sRed[wv][c]  = pp;
        sRedQ[wv][c] = qp;
        __syncthreads();                               // B7
        if (wv == 0) {
            Pout[(size_t)bn_i * 64 + c] = eb1_n[c] + sRed[0][c] + sRed[1][c]
                                        + sRed[2][c] + sRed[3][c];
            Qout[(size_t)bn_i * 64 + c] = sRedQ[0][c] + sRedQ[1][c]
                                        + sRedQ[2][c] + sRedQ[3][c]
                                        + spi * ew1_n[130 * 64 + c];
        }
        return;
    }

    if (wv != 0) return;

    // ---- wall MLP + final output (last layer only, wave 0) ----
    if (c < 4) {
        float px = sti.x, py = sti.y;
        float wd = (c == 0) ? px : (c == 1) ? 1.0f - px : (c == 2) ? py : 1.0f - py;
        scr[256 + c] = wd;
    }
    float t2 = wb1[c];
#pragma unroll 4
    for (int k = 0; k < 64; k++) t2 += scr[192 + k] * ww1[k * 64 + c];
#pragma unroll
    for (int k = 0; k < 4; k++)  t2 += scr[256 + k] * ww1[(64 + k) * 64 + c];
    t2 = silu_f(t2);
    scr[320 + c] = t2;
    float u = wb2[c];
#pragma unroll 8
    for (int k = 0; k < 64; k++) u += scr[320 + k] * ww2[k * 64 + c];
    u = silu_f(u);
    scr[384 + c] = u;
    if (c < 4) {
        float mg = wb3[c];
        for (int k = 0; k < 64; k++) mg += scr[384 + k] * ww3[k * 4 + c];
        scr[448 + c] = mg;
    }
    if (c == 0) {
        float fxl = sF[0][0] + sF[1][0] + sF[2][0] + sF[3][0];
        float fyl = sF[0][1] + sF[1][1] + sF[2][1] + sF[3][1];
        float fx = faccum[bn_i * 2 + 0] + fxl + (scr[448 + 0] - scr[448 + 1]);
        float fy = faccum[bn_i * 2 + 1] + fyl + (scr[448 + 2] - scr[448 + 3]);
        out[bn_i * 2 + 0] = fx;
        out[bn_i * 2 + 1] = fy;
    }
}

// ---------------------------------------------------------------------------
extern "C" void kernel_launch(void* const* d_in, const int* in_sizes, int n_in,
                              void* d_out, int out_size, void* d_ws, size_t ws_size,
                              hipStream_t stream)
{
    const float* state = (const float*)d_in[0];
    const float* hiw   = (const float*)d_in[1];
    const float* hib   = (const float*)d_in[2];
    const float* ew1   = (const float*)d_in[3];   // (3,132,64)
    const float* eb1   = (const float*)d_in[4];   // (3,64)
    const float* ew2   = (const float*)d_in[5];   // (3,64,64)
    const float* eb2   = (const float*)d_in[6];
    const float* fw1   = (const float*)d_in[7];   // (3,64,64)
    const float* fb1   = (const float*)d_in[8];
    const float* fw2   = (const float*)d_in[9];   // (3,64,1)
    const float* fb2   = (const float*)d_in[10];  // (3,1)
    const float* nw1   = (const float*)d_in[11];  // (3,128,64)
    const float* nb1   = (const float*)d_in[12];
    const float* nw2   = (const float*)d_in[13];  // (3,64,64)
    const float* nb2   = (const float*)d_in[14];
    const float* ww1   = (const float*)d_in[15];  // (68,64)
    const float* wb1   = (const float*)d_in[16];
    const float* ww2   = (const float*)d_in[17];  // (64,64)
    const float* wb2   = (const float*)d_in[18];
    const float* ww3   = (const float*)d_in[19];  // (64,4)
    const float* wb3   = (const float*)d_in[20];
    float* out = (float*)d_out;

    float* ws     = (float*)d_ws;
    float* h      = ws;                               // NB*NN*H
    float* P0     = h      + (size_t)NB * NN * H;
    float* Q0     = P0     + (size_t)NB * NN * H;
    float* P1     = Q0     + (size_t)NB * NN * H;     // ping-pong pair
    float* Q1     = P1     + (size_t)NB * NN * H;
    float* faccum = Q1     + (size_t)NB * NN * H;     // NB*NN*2
    float* wpackf = faccum + (size_t)NB * NN * 2;
    uint4* wpack  = (uint4*)(((uintptr_t)wpackf + 15) & ~(uintptr_t)15);

    float* Pb[2] = { P0, P1 };
    float* Qb[2] = { Q0, Q1 };

    k_setup<<<NBLK, 256, 0, stream>>>(state, hiw, hib, ew1, eb1,
                                      ew2, fw1, h, P0, Q0, faccum, wpack);

    for (int l = 0; l < NL; l++) {
        const int last = (l == NL - 1) ? 1 : 0;
        const int nl = last ? 0 : (l + 1);
        const int cur = l & 1, nxt = (l + 1) & 1;
        k_edge<<<dim3(NN, NB), 256, 0, stream>>>(
            state, Pb[cur], Qb[cur], Pb[nxt], Qb[nxt],
            ew1 + (size_t)l * 132 * 64,
            wpack + (size_t)l * 1024,
            eb2 + (size_t)l * 64,
            fb1 + (size_t)l * 64,
            fw2 + (size_t)l * 64, fb2 + (size_t)l,
            h, faccum,
            nw1 + (size_t)l * 128 * 64, nb1 + (size_t)l * 64,
            nw2 + (size_t)l * 64 * 64,  nb2 + (size_t)l * 64,
            ew1 + (size_t)nl * 132 * 64, eb1 + (size_t)nl * 64,
            ww1, wb1, ww2, wb2, ww3, wb3,
            out, last);
    }
}